// Round 1
// baseline (64.750 us; speedup 1.0000x reference)
//
#include <hip/hip_runtime.h>
#include <hip/hip_bf16.h>

// out[d,t] = (sum_j exp(s[t,j]) * u[j,d]) / (sum_j exp(s[t,j]))
// Single-pass fused exp-GEMM with a ones-column appended to U so numerator and
// denominator come out of the same MFMA accumulators.
//
// B_packed (in d_ws): U_ext[512][144] bf16 pre-packed in MFMA-B fragment order:
//   [kk(16)][nf(9)][lane(64)][i(8)]  where  k = kk*32 + 8*(lane>>4) + i,
//   col = nf*16 + (lane&15);  col 128 == 1.0 (ones), cols 129..143 == 0.
// Total 147456 bytes — L2-resident, read coalesced per K-step.

constexpr int T_DIM = 65536;
constexpr int J_DIM = 512;
constexpr int D_DIM = 128;
constexpr int KK_STEPS = J_DIM / 32;   // 16
constexpr int NFRAG = 9;               // 8 N-fragments for D=128 + 1 ones-column

typedef __attribute__((ext_vector_type(4))) float  f32x4;
typedef __attribute__((ext_vector_type(8))) short  s16x8;
typedef __attribute__((ext_vector_type(8))) __bf16 bf16x8;

__device__ __forceinline__ short f2bf_rne(float f) {
    unsigned u = __builtin_bit_cast(unsigned, f);
    u += 0x7fffu + ((u >> 16) & 1u);   // round-to-nearest-even
    return (short)(u >> 16);
}

__global__ __launch_bounds__(256) void prep_b(const float* __restrict__ u,
                                              short* __restrict__ bp) {
    int tid = blockIdx.x * blockDim.x + threadIdx.x;
    if (tid >= KK_STEPS * NFRAG * 64) return;
    int l  = tid & 63;
    int nf = (tid >> 6) % NFRAG;
    int kk = tid / (64 * NFRAG);
    int d  = nf * 16 + (l & 15);
    int k0 = kk * 32 + 8 * (l >> 4);
    s16x8 o;
#pragma unroll
    for (int i = 0; i < 8; ++i) {
        float v = (nf < 8) ? u[(size_t)(k0 + i) * D_DIM + d]
                           : (((l & 15) == 0) ? 1.0f : 0.0f);
        o[i] = f2bf_rne(v);
    }
    *reinterpret_cast<s16x8*>(bp + (size_t)tid * 8) = o;
}

__global__ __launch_bounds__(256, 4) void c2q_main(const float* __restrict__ sm,
                                                   const short* __restrict__ bp,
                                                   float* __restrict__ out) {
    const int tid  = threadIdx.x;
    const int l    = tid & 63;
    const int w    = tid >> 6;        // wave 0..3
    const int lmod = l & 15;
    const int lh   = l >> 4;          // 0..3
    const int r0   = blockIdx.x * 64 + w * 16;   // this wave's first t-row

    f32x4 acc[NFRAG];
#pragma unroll
    for (int nf = 0; nf < NFRAG; ++nf) acc[nf] = (f32x4){0.f, 0.f, 0.f, 0.f};

    // A fragment loads straight from global: lane holds rows r0+lmod,
    // k = kk*32 + 8*lh + i  -> 8 contiguous floats (32B) per lane per step.
    const float* sp = sm + (size_t)(r0 + lmod) * J_DIM + lh * 8;
    const short* bl = bp + l * 8;

    for (int kk = 0; kk < KK_STEPS; ++kk) {
        f32x4 s0 = *reinterpret_cast<const f32x4*>(sp);
        f32x4 s1 = *reinterpret_cast<const f32x4*>(sp + 4);
        sp += 32;
        s16x8 a;
        a[0] = f2bf_rne(__expf(s0[0]));
        a[1] = f2bf_rne(__expf(s0[1]));
        a[2] = f2bf_rne(__expf(s0[2]));
        a[3] = f2bf_rne(__expf(s0[3]));
        a[4] = f2bf_rne(__expf(s1[0]));
        a[5] = f2bf_rne(__expf(s1[1]));
        a[6] = f2bf_rne(__expf(s1[2]));
        a[7] = f2bf_rne(__expf(s1[3]));
        bf16x8 av = __builtin_bit_cast(bf16x8, a);
        const short* bk = bl + kk * (NFRAG * 64 * 8);
#pragma unroll
        for (int nf = 0; nf < NFRAG; ++nf) {
            bf16x8 bv = __builtin_bit_cast(bf16x8,
                *reinterpret_cast<const s16x8*>(bk + nf * 512));
            acc[nf] = __builtin_amdgcn_mfma_f32_16x16x32_bf16(av, bv, acc[nf], 0, 0, 0);
        }
    }

    // Denominator lives in acc[8] (ones-column, col offset 0 -> lanes with lmod==0),
    // reg r corresponds to t-row r0 + 4*lh + r. Broadcast within each 16-lane group.
    float inv[4];
#pragma unroll
    for (int r = 0; r < 4; ++r) {
        float den = __shfl(acc[8][r], (l & 48), 64);
        inv[r] = 1.0f / den;
    }

    // C/D layout: col = lane&15 (-> d), row = 4*(lane>>4)+reg (-> t, 4 consecutive).
    // Store 4 consecutive t per lane as one dwordx4.
#pragma unroll
    for (int nf = 0; nf < 8; ++nf) {
        f32x4 v;
#pragma unroll
        for (int r = 0; r < 4; ++r) v[r] = acc[nf][r] * inv[r];
        *reinterpret_cast<f32x4*>(out + (size_t)(nf * 16 + lmod) * T_DIM
                                  + r0 + 4 * lh) = v;
    }
}

extern "C" void kernel_launch(void* const* d_in, const int* in_sizes, int n_in,
                              void* d_out, int out_size, void* d_ws, size_t ws_size,
                              hipStream_t stream) {
    const float* u = (const float*)d_in[0];   // (1, 512, 128) fp32
    const float* s = (const float*)d_in[1];   // (65536, 512) fp32
    float* out = (float*)d_out;               // (128, 65536) fp32
    short* bp = (short*)d_ws;                 // 147456 bytes used

    prep_b<<<(KK_STEPS * NFRAG * 64 + 255) / 256, 256, 0, stream>>>(u, bp);
    c2q_main<<<T_DIM / 64, 256, 0, stream>>>(s, bp, out);
}

// Round 2
// 48.749 us; speedup vs baseline: 1.3282x; 1.3282x over previous
//
#include <hip/hip_runtime.h>
#include <hip/hip_bf16.h>

// out[d,t] = (sum_j exp(s[t,j]) * u[j,d]) / (sum_j exp(s[t,j]))
// Fused exp-GEMM (ones-column in B gives the denominator from the same MFMAs).
// R2 change: depth-8 software-pipelined s-loads (rotating register buffer,
// fully unrolled K-loop) so each wave keeps 8 KB of HBM loads in flight
// instead of 1 dependent load per iteration.

constexpr int T_DIM = 65536;
constexpr int J_DIM = 512;
constexpr int D_DIM = 128;
constexpr int KK_STEPS = J_DIM / 32;   // 16
constexpr int NFRAG = 9;               // 8 N-fragments for D=128 + 1 ones-column
constexpr int PF_DEPTH = 8;            // s-load prefetch depth (iterations)

typedef __attribute__((ext_vector_type(4))) float  f32x4;
typedef __attribute__((ext_vector_type(8))) short  s16x8;
typedef __attribute__((ext_vector_type(8))) __bf16 bf16x8;

__device__ __forceinline__ short f2bf_rne(float f) {
    unsigned u = __builtin_bit_cast(unsigned, f);
    u += 0x7fffu + ((u >> 16) & 1u);   // round-to-nearest-even
    return (short)(u >> 16);
}

__global__ __launch_bounds__(256) void prep_b(const float* __restrict__ u,
                                              short* __restrict__ bp) {
    int tid = blockIdx.x * blockDim.x + threadIdx.x;
    if (tid >= KK_STEPS * NFRAG * 64) return;
    int l  = tid & 63;
    int nf = (tid >> 6) % NFRAG;
    int kk = tid / (64 * NFRAG);
    int d  = nf * 16 + (l & 15);
    int k0 = kk * 32 + 8 * (l >> 4);
    s16x8 o;
#pragma unroll
    for (int i = 0; i < 8; ++i) {
        float v = (nf < 8) ? u[(size_t)(k0 + i) * D_DIM + d]
                           : (((l & 15) == 0) ? 1.0f : 0.0f);
        o[i] = f2bf_rne(v);
    }
    *reinterpret_cast<s16x8*>(bp + (size_t)tid * 8) = o;
}

__global__ __launch_bounds__(256) void c2q_main(const float* __restrict__ sm,
                                                const short* __restrict__ bp,
                                                float* __restrict__ out) {
    const int tid  = threadIdx.x;
    const int l    = tid & 63;
    const int w    = tid >> 6;        // wave 0..3
    const int lmod = l & 15;
    const int lh   = l >> 4;          // 0..3
    const int r0   = blockIdx.x * 64 + w * 16;   // this wave's first t-row

    // A fragment loads straight from global: lane holds row r0+lmod,
    // k = kk*32 + 8*lh + i  -> 8 contiguous floats (32B) per lane per step.
    const float* sp = sm + (size_t)(r0 + lmod) * J_DIM + lh * 8;
    const short* bl = bp + l * 8;

    f32x4 acc[NFRAG];
#pragma unroll
    for (int nf = 0; nf < NFRAG; ++nf) acc[nf] = (f32x4){0.f, 0.f, 0.f, 0.f};

    // ---- depth-8 rotating prefetch buffer (all indices static via unroll) ----
    f32x4 sbuf[PF_DEPTH][2];
#pragma unroll
    for (int p = 0; p < PF_DEPTH; ++p) {
        sbuf[p][0] = *reinterpret_cast<const f32x4*>(sp + p * 32);
        sbuf[p][1] = *reinterpret_cast<const f32x4*>(sp + p * 32 + 4);
    }

#pragma unroll
    for (int kk = 0; kk < KK_STEPS; ++kk) {
        f32x4 s0 = sbuf[kk & (PF_DEPTH - 1)][0];
        f32x4 s1 = sbuf[kk & (PF_DEPTH - 1)][1];
        // re-issue this slot for iteration kk+PF_DEPTH (folds at compile time)
        if (kk + PF_DEPTH < KK_STEPS) {
            sbuf[kk & (PF_DEPTH - 1)][0] =
                *reinterpret_cast<const f32x4*>(sp + (kk + PF_DEPTH) * 32);
            sbuf[kk & (PF_DEPTH - 1)][1] =
                *reinterpret_cast<const f32x4*>(sp + (kk + PF_DEPTH) * 32 + 4);
        }
        s16x8 a;
        a[0] = f2bf_rne(__expf(s0[0]));
        a[1] = f2bf_rne(__expf(s0[1]));
        a[2] = f2bf_rne(__expf(s0[2]));
        a[3] = f2bf_rne(__expf(s0[3]));
        a[4] = f2bf_rne(__expf(s1[0]));
        a[5] = f2bf_rne(__expf(s1[1]));
        a[6] = f2bf_rne(__expf(s1[2]));
        a[7] = f2bf_rne(__expf(s1[3]));
        bf16x8 av = __builtin_bit_cast(bf16x8, a);
        const short* bk = bl + kk * (NFRAG * 64 * 8);
#pragma unroll
        for (int nf = 0; nf < NFRAG; ++nf) {
            bf16x8 bv = __builtin_bit_cast(bf16x8,
                *reinterpret_cast<const s16x8*>(bk + nf * 512));
            acc[nf] = __builtin_amdgcn_mfma_f32_16x16x32_bf16(av, bv, acc[nf], 0, 0, 0);
        }
    }

    // Denominator lives in acc[8] (ones-column -> col 0 of that fragment),
    // reg r corresponds to t-row r0 + 4*lh + r. Broadcast within 16-lane group.
    float inv[4];
#pragma unroll
    for (int r = 0; r < 4; ++r) {
        float den = __shfl(acc[8][r], (l & 48), 64);
        inv[r] = 1.0f / den;
    }

    // C/D layout: col = lane&15 (-> d), row = 4*(lane>>4)+reg (-> t).
#pragma unroll
    for (int nf = 0; nf < 8; ++nf) {
        f32x4 v;
#pragma unroll
        for (int r = 0; r < 4; ++r) v[r] = acc[nf][r] * inv[r];
        *reinterpret_cast<f32x4*>(out + (size_t)(nf * 16 + lmod) * T_DIM
                                  + r0 + 4 * lh) = v;
    }
}

extern "C" void kernel_launch(void* const* d_in, const int* in_sizes, int n_in,
                              void* d_out, int out_size, void* d_ws, size_t ws_size,
                              hipStream_t stream) {
    const float* u = (const float*)d_in[0];   // (1, 512, 128) fp32
    const float* s = (const float*)d_in[1];   // (65536, 512) fp32
    float* out = (float*)d_out;               // (128, 65536) fp32
    short* bp = (short*)d_ws;                 // 147456 bytes used

    prep_b<<<(KK_STEPS * NFRAG * 64 + 255) / 256, 256, 0, stream>>>(u, bp);
    c2q_main<<<T_DIM / 64, 256, 0, stream>>>(s, bp, out);
}